// Round 1
// baseline (116.713 us; speedup 1.0000x reference)
//
#include <hip/hip_runtime.h>

// CensusLoss: mean |census(pred) - census(target)| with 7x7 census on grayscale,
// reflect padding. Census bits are 0/1 -> loss = mismatch_count / (B*48*H*W).
// Single fused kernel: gray-on-the-fly into LDS halo tile, sliding-column
// register window (8 rows/thread) to minimize ds_read traffic, integer count,
// block reduce, one float atomicAdd of the scaled partial.

#define BATCH 8
#define HH 512
#define WW 512
#define PLANE (HH * WW)
#define TILE_W 32
#define TILE_H 64          // 8 thread-rows x 8 pixel-rows each
#define LT_W 38            // TILE_W + 6 halo
#define LT_H 70            // TILE_H + 6 halo
#define LT_PITCH 39        // +1 pad (2-way bank aliasing only -> free)
#define RPT 8              // pixel rows per thread

__global__ __launch_bounds__(256)
void census_loss_kernel(const float* __restrict__ pred,
                        const float* __restrict__ target,
                        float* __restrict__ out) {
    __shared__ float sP[LT_H][LT_PITCH];
    __shared__ float sT[LT_H][LT_PITCH];

    const int b = blockIdx.z;
    const int ty0 = blockIdx.y * TILE_H;
    const int tx0 = blockIdx.x * TILE_W;
    const float* __restrict__ pb = pred + (size_t)b * 3 * PLANE;
    const float* __restrict__ tb = target + (size_t)b * 3 * PLANE;

    // Stage gray halo tile (reflect indexing). Same expression everywhere ->
    // bit-identical gray for a given pixel regardless of which block computes it.
    for (int idx = threadIdx.x; idx < LT_H * LT_W; idx += 256) {
        const int ly = idx / LT_W;
        const int lx = idx - ly * LT_W;
        int gy = ty0 + ly - 3;
        int gx = tx0 + lx - 3;
        gy = gy < 0 ? -gy : (gy >= HH ? 2 * HH - 2 - gy : gy);
        gx = gx < 0 ? -gx : (gx >= WW ? 2 * WW - 2 - gx : gx);
        const int off = gy * WW + gx;
        sP[ly][lx] = 0.299f * pb[off] + 0.587f * pb[off + PLANE] + 0.114f * pb[off + 2 * PLANE];
        sT[ly][lx] = 0.299f * tb[off] + 0.587f * tb[off + PLANE] + 0.114f * tb[off + 2 * PLANE];
    }
    __syncthreads();

    const int c   = threadIdx.x & 31;         // tile column
    const int pr0 = (threadIdx.x >> 5) * RPT; // first pixel row of this thread

    // Centers: pixel (pr0+p, c) -> sX[pr0+p+3][c+3]
    float cP[RPT], cT[RPT];
    #pragma unroll
    for (int p = 0; p < RPT; ++p) {
        cP[p] = sP[pr0 + p + 3][c + 3];
        cT[p] = sT[pr0 + p + 3][c + 3];
    }

    int cnt = 0;
    #pragma unroll
    for (int j = 0; j < 7; ++j) {
        // Column window: rows pr0 .. pr0+13 cover all 8 pixels' 7-row windows.
        float vP[RPT + 6], vT[RPT + 6];
        #pragma unroll
        for (int i = 0; i < RPT + 6; ++i) {
            vP[i] = sP[pr0 + i][c + j];
            vT[i] = sT[pr0 + i][c + j];
        }
        #pragma unroll
        for (int p = 0; p < RPT; ++p) {
            #pragma unroll
            for (int i = 0; i < 7; ++i) {
                if (j == 3 && i == 3) continue;  // skip center
                const bool bp = cP[p] > vP[p + i];
                const bool bt = cT[p] > vT[p + i];
                cnt += (bp != bt) ? 1 : 0;
            }
        }
    }

    // 64-lane wave reduction, then cross-wave via LDS.
    #pragma unroll
    for (int offs = 32; offs > 0; offs >>= 1)
        cnt += __shfl_down(cnt, offs, 64);

    __shared__ int wsum[4];
    if ((threadIdx.x & 63) == 0) wsum[threadIdx.x >> 6] = cnt;
    __syncthreads();
    if (threadIdx.x == 0) {
        const int total = wsum[0] + wsum[1] + wsum[2] + wsum[3];
        // N = 8 * 48 * 512 * 512 = 100663296
        atomicAdd(out, (float)total * (1.0f / 100663296.0f));
    }
}

extern "C" void kernel_launch(void* const* d_in, const int* in_sizes, int n_in,
                              void* d_out, int out_size, void* d_ws, size_t ws_size,
                              hipStream_t stream) {
    const float* pred   = (const float*)d_in[0];
    const float* target = (const float*)d_in[1];
    float* out = (float*)d_out;

    // d_out is re-poisoned to 0xAA before every timed launch -> zero it on-stream.
    hipMemsetAsync(out, 0, sizeof(float), stream);

    dim3 grid(WW / TILE_W, HH / TILE_H, BATCH);  // (16, 8, 8) = 1024 blocks
    census_loss_kernel<<<grid, 256, 0, stream>>>(pred, target, out);
}